// Round 10
// baseline (219.111 us; speedup 1.0000x reference)
//
#include <hip/hip_runtime.h>
#include <math.h>

#define HH 96
#define WW 96
#define CC 64
#define NH 4
#define HD 16
#define KS 13
#define KK (KS*KS)
#define NTOK (HH*WW)

// ---------------- DPP cross-lane add (pure VALU, no LDS pipe) ---------------
// ctrl 0xB1 = quad_perm(1,0,3,2)  -> xor1 within quad
// ctrl 0x4E = quad_perm(2,3,0,1)  -> xor2 within quad
// ctrl 0x124 = row_ror:4, 0x128 = row_ror:8 (full-group sums: direction moot)
// ctrl 0x141 = row_half_mirror, 0x140 = row_mirror (valid when sub-groups
// already uniform)
template<int CTRL>
__device__ __forceinline__ float dpp_add(float p) {
    int t = __builtin_amdgcn_update_dpp(0, __float_as_int(p), CTRL, 0xF, 0xF, true);
    return p + __int_as_float(t);
}

__device__ __forceinline__ float dpp_reduce8(float p) {
    p = dpp_add<0xB1>(p);
    p = dpp_add<0x4E>(p);
    p = dpp_add<0x141>(p);
    return p;
}
__device__ __forceinline__ float dpp_reduce16(float p) {
    p = dpp_reduce8(p);
    p = dpp_add<0x140>(p);
    return p;
}

// In-place LayerNorm of a 32-token tile stored TRANSPOSED in LDS: buf[ch][tok],
// ch = 0..63, tok = 0..31. 256 threads: 8 lanes per row, 8 channels per lane.
__device__ __forceinline__ void ln_rows32(float (*buf)[34],
                                          const float* __restrict__ g,
                                          const float* __restrict__ b,
                                          int tid) {
    int r  = tid >> 3;
    int c0 = (tid & 7) * 8;
    float v[8];
    float s = 0.0f;
    #pragma unroll
    for (int j = 0; j < 8; j++) { v[j] = buf[c0 + j][r]; s += v[j]; }
    s = dpp_reduce8(s);
    float mu = s * (1.0f / 64.0f);
    float s2 = 0.0f;
    #pragma unroll
    for (int j = 0; j < 8; j++) { float d = v[j] - mu; s2 += d * d; }
    s2 = dpp_reduce8(s2);
    float inv = rsqrtf(s2 * (1.0f / 64.0f) + 1e-5f);
    #pragma unroll
    for (int j = 0; j < 8; j++)
        buf[c0 + j][r] = (v[j] - mu) * inv * g[c0 + j] + b[c0 + j];
}

// ---------------- Fused LN1 + qkv GEMM --------------------------------------
__global__ __launch_bounds__(256) void ln_gemm_kernel(const float* __restrict__ x,
                                                      const float* __restrict__ g,
                                                      const float* __restrict__ b,
                                                      const float* __restrict__ W,
                                                      const float* __restrict__ bias,
                                                      float* __restrict__ out) {
    __shared__ float Ast[64][34];
    const int t0 = blockIdx.x * 32;
    const int tid = threadIdx.x;

    for (int i = tid; i < 32 * 64; i += 256) {
        int r = i >> 6, cc = i & 63;
        Ast[cc][r] = x[t0 * 64 + i];
    }
    __syncthreads();
    ln_rows32(Ast, g, b, tid);
    __syncthreads();

    const int tc = tid & 15;
    const int tr = tid >> 4;
    const int r0 = tr * 2;
    const int c  = blockIdx.y * 64 + tc * 4;

    float4 b4 = *(const float4*)&bias[c];
    float4 acc0 = b4, acc1 = b4;
    #pragma unroll 8
    for (int k = 0; k < 64; k++) {
        float2 a = *(const float2*)&Ast[k][r0];
        float4 w = *(const float4*)&W[k * 192 + c];
        acc0.x += a.x * w.x; acc0.y += a.x * w.y; acc0.z += a.x * w.z; acc0.w += a.x * w.w;
        acc1.x += a.y * w.x; acc1.y += a.y * w.y; acc1.z += a.y * w.z; acc1.w += a.y * w.w;
    }
    if (blockIdx.y == 0) {  // q section scaled by hd^-0.5 = 0.25
        acc0.x *= 0.25f; acc0.y *= 0.25f; acc0.z *= 0.25f; acc0.w *= 0.25f;
        acc1.x *= 0.25f; acc1.y *= 0.25f; acc1.z *= 0.25f; acc1.w *= 0.25f;
    }
    *(float4*)&out[(t0 + r0) * 192 + c] = acc0;
    *(float4*)&out[(t0 + r0 + 1) * 192 + c] = acc1;
}

// ---------------- Neighborhood attention: one wave per token ----------------
// (unchanged from R8: slot-variant inner loop, window-sharing block
// composition, XCD swizzle)
__global__ __launch_bounds__(256) void na_attn_kernel(const float* __restrict__ qkv,
                                                      const float* __restrict__ rpb,
                                                      float* __restrict__ out) {
    int wave = threadIdx.x >> 6;
    int lane = threadIdx.x & 63;
    int bid  = blockIdx.x;
    int swz  = (bid & 7) * 288 + (bid >> 3);   // bijective: 2304 % 8 == 0
    int y    = swz / 24;                       // spatial row
    int rem  = swz - y * 24;
    int gw   = rem >> 3;                       // dilation group (x % 3)
    int iw   = (rem & 7) * 4 + wave;           // group-col of this wave's token
    int token = y * WW + gw + 3 * iw;

    int head = lane >> 4;
    int slot = (lane >> 2) & 3;
    int l    = lane & 3;
    int co   = head * HD + l * 4;

    int gh = y % 3, ih = y / 3;
    int sh = ih - 6; sh = sh < 0 ? 0 : (sh > 19 ? 19 : sh);
    int sw = iw - 6; sw = sw < 0 ? 0 : (sw > 19 ? 19 : sw);

    float4 q4 = *(const float4*)&qkv[token * 192 + co];
    const float* bias_h = rpb + head * 625 + (sw - iw + 12);

    const int xpart = (gw + 3 * sw) * 192 + 64 + co + slot * 576;

    float4 acc = make_float4(0.f, 0.f, 0.f, 0.f);
    float s = 0.0f;

    for (int kh = 0; kh < KS; kh++) {
        int ny = gh + 3 * (sh + kh);
        const float* kp = qkv + ny * (WW * 192) + xpart;
        const float* bp = bias_h + (sh + kh - ih + 12) * 25;
        #pragma unroll
        for (int i = 0; i < 3; i++) {          // kw = 4*i + slot : 0..11
            float4 k4 = *(const float4*)(kp + i * 2304);
            float4 v4 = *(const float4*)(kp + i * 2304 + 64);
            float p = q4.x * k4.x + q4.y * k4.y + q4.z * k4.z + q4.w * k4.w;
            p = dpp_add<0xB1>(p);
            p = dpp_add<0x4E>(p);              // p = 16-dim dot (quad sum)
            float e = __expf(p + bp[4 * i + slot]);
            s += e;
            acc.x += e * v4.x; acc.y += e * v4.y; acc.z += e * v4.z; acc.w += e * v4.w;
        }
        if (slot == 0) {                        // tail kw = 12 (quad-uniform branch)
            float4 k4 = *(const float4*)(kp + 3 * 2304);
            float4 v4 = *(const float4*)(kp + 3 * 2304 + 64);
            float p = q4.x * k4.x + q4.y * k4.y + q4.z * k4.z + q4.w * k4.w;
            p = dpp_add<0xB1>(p);
            p = dpp_add<0x4E>(p);
            float e = __expf(p + bp[12]);
            s += e;
            acc.x += e * v4.x; acc.y += e * v4.y; acc.z += e * v4.z; acc.w += e * v4.w;
        }
    }

    s = dpp_add<0x128>(s);  s = dpp_add<0x124>(s);
    acc.x = dpp_add<0x128>(acc.x); acc.x = dpp_add<0x124>(acc.x);
    acc.y = dpp_add<0x128>(acc.y); acc.y = dpp_add<0x124>(acc.y);
    acc.z = dpp_add<0x128>(acc.z); acc.z = dpp_add<0x124>(acc.z);
    acc.w = dpp_add<0x128>(acc.w); acc.w = dpp_add<0x124>(acc.w);

    if (slot == 0) {
        float inv = 1.0f / s;
        *(float4*)&out[token * CC + co] =
            make_float4(acc.x * inv, acc.y * inv, acc.z * inv, acc.w * inv);
    }
}

// ---------------- Fused proj+resid -> LN2 -> fc1+gelu -> fc2+resid ----------
// RETILED FOR OCCUPANCY (R8 diagnosis: 288 blocks -> 1.1 wave/SIMD -> 42 us
// latency-starved at 10% occupancy, 11.5% VALUBusy).
// Now: 8 tokens/block, 256 threads, grid 1152 -> 4.5 blocks/CU = 4.5
// waves/SIMD, and per-thread serial work drops 4x (1 row x float2 cols).
// Thread map: tr = tid>>5 (row 0..7), tc = tid&31 (col pair 2tc,2tc+1).
// x2 still carried in registers from proj-resid to fc2-resid (same thread
// owns the same row/cols in both). LDS 13.8 KB, pitch 9 -> reads are
// broadcast (row index uniform per wave-half), writes <=2-way.
__global__ __launch_bounds__(256) void mlp_fused_kernel(const float* __restrict__ attn_out,
                                                        const float* __restrict__ x,
                                                        const float* __restrict__ proj_w,
                                                        const float* __restrict__ proj_b,
                                                        const float* __restrict__ n2g,
                                                        const float* __restrict__ n2b,
                                                        const float* __restrict__ fc1_w,
                                                        const float* __restrict__ fc1_b,
                                                        const float* __restrict__ fc2_w,
                                                        const float* __restrict__ fc2_b,
                                                        float* __restrict__ out) {
    __shared__ float Ast[64][9];     // attn_out^T tile (8 tokens)
    __shared__ float X2T[64][9];     // x2^T, then h2^T after LN
    __shared__ float Hid[256][9];    // hidden^T (gelu(fc1)) for fc2

    const int t0 = blockIdx.x * 8;
    const int tid = threadIdx.x;
    const int tc = tid & 31;         // col-pair: cols 2tc, 2tc+1
    const int tr = tid >> 5;         // row 0..7
    const int c2 = tc * 2;

    // stage attn_out tile transposed: 512 floats, 2 per thread (float2 load)
    {
        float2 v = *(const float2*)&attn_out[t0 * 64 + tid * 2];
        int i = tid * 2;
        int r = i >> 6, cc = i & 63;
        Ast[cc][r] = v.x;
        Ast[cc + 1][r] = v.y;
    }
    __syncthreads();

    // ---- proj + residual(x): x2 kept in registers (a0) ----
    float2 a0 = *(const float2*)&proj_b[c2];
    #pragma unroll 8
    for (int k = 0; k < 64; k++) {
        float a = Ast[k][tr];
        float2 w = *(const float2*)&proj_w[k * 64 + c2];
        a0.x += a * w.x; a0.y += a * w.y;
    }
    {
        float2 xr = *(const float2*)&x[(t0 + tr) * 64 + c2];
        a0.x += xr.x; a0.y += xr.y;
    }
    X2T[c2][tr] = a0.x; X2T[c2 + 1][tr] = a0.y;
    __syncthreads();

    // ---- LN2 in place on X2T (waves 0-1: 16 lanes/token, 4 ch/lane) ----
    if (tid < 128) {
        int r  = tid >> 4;
        int c0 = (tid & 15) * 4;
        float v[4];
        float s = 0.0f;
        #pragma unroll
        for (int j = 0; j < 4; j++) { v[j] = X2T[c0 + j][r]; s += v[j]; }
        s = dpp_reduce16(s);
        float mu = s * (1.0f / 64.0f);
        float s2 = 0.0f;
        #pragma unroll
        for (int j = 0; j < 4; j++) { float d = v[j] - mu; s2 += d * d; }
        s2 = dpp_reduce16(s2);
        float inv = rsqrtf(s2 * (1.0f / 64.0f) + 1e-5f);
        #pragma unroll
        for (int j = 0; j < 4; j++)
            X2T[c0 + j][r] = (v[j] - mu) * inv * n2g[c0 + j] + n2b[c0 + j];
    }
    __syncthreads();

    // ---- fc1 + gelu -> Hid. Each thread: 1 row x 8 cols (4 gg x float2) ----
    float2 h[4];
    #pragma unroll
    for (int gg = 0; gg < 4; gg++)
        h[gg] = *(const float2*)&fc1_b[c2 + gg * 64];
    #pragma unroll 4
    for (int k = 0; k < 64; k++) {
        float a = X2T[k][tr];
        #pragma unroll
        for (int gg = 0; gg < 4; gg++) {
            float2 w = *(const float2*)&fc1_w[k * 256 + c2 + gg * 64];
            h[gg].x += a * w.x; h[gg].y += a * w.y;
        }
    }
    #define GELU1(v) v = 0.5f * v * (1.0f + erff(v * 0.70710678118f))
    #pragma unroll
    for (int gg = 0; gg < 4; gg++) { GELU1(h[gg].x); GELU1(h[gg].y); }
    #undef GELU1
    #pragma unroll
    for (int gg = 0; gg < 4; gg++) {
        Hid[c2 + gg * 64][tr]     = h[gg].x;
        Hid[c2 + 1 + gg * 64][tr] = h[gg].y;
    }
    __syncthreads();

    // ---- fc2 + residual(x2 from registers) ----
    float2 o = *(const float2*)&fc2_b[c2];
    #pragma unroll 8
    for (int k = 0; k < 256; k++) {
        float a = Hid[k][tr];
        float2 w = *(const float2*)&fc2_w[k * 64 + c2];
        o.x += a * w.x; o.y += a * w.y;
    }
    o.x += a0.x; o.y += a0.y;
    *(float2*)&out[(t0 + tr) * 64 + c2] = o;
}

extern "C" void kernel_launch(void* const* d_in, const int* in_sizes, int n_in,
                              void* d_out, int out_size, void* d_ws, size_t ws_size,
                              hipStream_t stream) {
    const float* x       = (const float*)d_in[0];
    const float* norm1_g = (const float*)d_in[1];
    const float* norm1_b = (const float*)d_in[2];
    const float* qkv_w   = (const float*)d_in[3];
    const float* qkv_b   = (const float*)d_in[4];
    const float* rpb     = (const float*)d_in[5];
    const float* proj_w  = (const float*)d_in[6];
    const float* proj_b  = (const float*)d_in[7];
    const float* norm2_g = (const float*)d_in[8];
    const float* norm2_b = (const float*)d_in[9];
    const float* fc1_w   = (const float*)d_in[10];
    const float* fc1_b   = (const float*)d_in[11];
    const float* fc2_w   = (const float*)d_in[12];
    const float* fc2_b   = (const float*)d_in[13];
    float* out = (float*)d_out;

    float* ws = (float*)d_ws;
    float* qkv      = ws;                      // 9216*192
    float* attn_out = qkv + NTOK * 192;        // 9216*64

    dim3 blk(256);
    // 1. qkv = LN1(x) @ qkv_w + qkv_b   (q pre-scaled)
    ln_gemm_kernel<<<dim3(NTOK / 32, 3), blk, 0, stream>>>(x, norm1_g, norm1_b, qkv_w, qkv_b, qkv);
    // 2. neighborhood attention (1 token/wave; block = 4 window-sharing tokens)
    na_attn_kernel<<<NTOK / 4, blk, 0, stream>>>(qkv, rpb, attn_out);
    // 3. out = fused proj+resid -> LN2 -> fc1+gelu -> fc2+resid (8 tok/block)
    mlp_fused_kernel<<<NTOK / 8, blk, 0, stream>>>(attn_out, x, proj_w, proj_b,
                                                   norm2_g, norm2_b, fc1_w, fc1_b,
                                                   fc2_w, fc2_b, out);
}

// Round 11
// 164.464 us; speedup vs baseline: 1.3323x; 1.3323x over previous
//
#include <hip/hip_runtime.h>
#include <math.h>

#define HH 96
#define WW 96
#define CC 64
#define NH 4
#define HD 16
#define KS 13
#define KK (KS*KS)
#define NTOK (HH*WW)

// ---------------- DPP cross-lane add (pure VALU, no LDS pipe) ---------------
// ctrl 0xB1 = quad_perm(1,0,3,2)  -> xor1 within quad
// ctrl 0x4E = quad_perm(2,3,0,1)  -> xor2 within quad
// ctrl 0x124 = row_ror:4, 0x128 = row_ror:8 (full-group sums: direction moot)
// ctrl 0x141 = row_half_mirror, 0x140 = row_mirror (valid when sub-groups
// already uniform)
template<int CTRL>
__device__ __forceinline__ float dpp_add(float p) {
    int t = __builtin_amdgcn_update_dpp(0, __float_as_int(p), CTRL, 0xF, 0xF, true);
    return p + __int_as_float(t);
}

__device__ __forceinline__ float dpp_reduce8(float p) {
    p = dpp_add<0xB1>(p);
    p = dpp_add<0x4E>(p);
    p = dpp_add<0x141>(p);
    return p;
}

// In-place LayerNorm of a 32-token tile stored TRANSPOSED in LDS: buf[ch][tok],
// ch = 0..63, tok = 0..31. 256 threads: 8 lanes per row, 8 channels per lane.
__device__ __forceinline__ void ln_rows32(float (*buf)[34],
                                          const float* __restrict__ g,
                                          const float* __restrict__ b,
                                          int tid) {
    int r  = tid >> 3;
    int c0 = (tid & 7) * 8;
    float v[8];
    float s = 0.0f;
    #pragma unroll
    for (int j = 0; j < 8; j++) { v[j] = buf[c0 + j][r]; s += v[j]; }
    s = dpp_reduce8(s);
    float mu = s * (1.0f / 64.0f);
    float s2 = 0.0f;
    #pragma unroll
    for (int j = 0; j < 8; j++) { float d = v[j] - mu; s2 += d * d; }
    s2 = dpp_reduce8(s2);
    float inv = rsqrtf(s2 * (1.0f / 64.0f) + 1e-5f);
    #pragma unroll
    for (int j = 0; j < 8; j++)
        buf[c0 + j][r] = (v[j] - mu) * inv * g[c0 + j] + b[c0 + j];
}

// ---------------- Fused LN1 + qkv GEMM (unchanged) --------------------------
__global__ __launch_bounds__(256) void ln_gemm_kernel(const float* __restrict__ x,
                                                      const float* __restrict__ g,
                                                      const float* __restrict__ b,
                                                      const float* __restrict__ W,
                                                      const float* __restrict__ bias,
                                                      float* __restrict__ out) {
    __shared__ float Ast[64][34];
    const int t0 = blockIdx.x * 32;
    const int tid = threadIdx.x;

    for (int i = tid; i < 32 * 64; i += 256) {
        int r = i >> 6, cc = i & 63;
        Ast[cc][r] = x[t0 * 64 + i];
    }
    __syncthreads();
    ln_rows32(Ast, g, b, tid);
    __syncthreads();

    const int tc = tid & 15;
    const int tr = tid >> 4;
    const int r0 = tr * 2;
    const int c  = blockIdx.y * 64 + tc * 4;

    float4 b4 = *(const float4*)&bias[c];
    float4 acc0 = b4, acc1 = b4;
    #pragma unroll 8
    for (int k = 0; k < 64; k++) {
        float2 a = *(const float2*)&Ast[k][r0];
        float4 w = *(const float4*)&W[k * 192 + c];
        acc0.x += a.x * w.x; acc0.y += a.x * w.y; acc0.z += a.x * w.z; acc0.w += a.x * w.w;
        acc1.x += a.y * w.x; acc1.y += a.y * w.y; acc1.z += a.y * w.z; acc1.w += a.y * w.w;
    }
    if (blockIdx.y == 0) {  // q section scaled by hd^-0.5 = 0.25
        acc0.x *= 0.25f; acc0.y *= 0.25f; acc0.z *= 0.25f; acc0.w *= 0.25f;
        acc1.x *= 0.25f; acc1.y *= 0.25f; acc1.z *= 0.25f; acc1.w *= 0.25f;
    }
    *(float4*)&out[(t0 + r0) * 192 + c] = acc0;
    *(float4*)&out[(t0 + r0 + 1) * 192 + c] = acc1;
}

// ---------------- Neighborhood attention (unchanged from R8) ----------------
__global__ __launch_bounds__(256) void na_attn_kernel(const float* __restrict__ qkv,
                                                      const float* __restrict__ rpb,
                                                      float* __restrict__ out) {
    int wave = threadIdx.x >> 6;
    int lane = threadIdx.x & 63;
    int bid  = blockIdx.x;
    int swz  = (bid & 7) * 288 + (bid >> 3);   // bijective: 2304 % 8 == 0
    int y    = swz / 24;                       // spatial row
    int rem  = swz - y * 24;
    int gw   = rem >> 3;                       // dilation group (x % 3)
    int iw   = (rem & 7) * 4 + wave;           // group-col of this wave's token
    int token = y * WW + gw + 3 * iw;

    int head = lane >> 4;
    int slot = (lane >> 2) & 3;
    int l    = lane & 3;
    int co   = head * HD + l * 4;

    int gh = y % 3, ih = y / 3;
    int sh = ih - 6; sh = sh < 0 ? 0 : (sh > 19 ? 19 : sh);
    int sw = iw - 6; sw = sw < 0 ? 0 : (sw > 19 ? 19 : sw);

    float4 q4 = *(const float4*)&qkv[token * 192 + co];
    const float* bias_h = rpb + head * 625 + (sw - iw + 12);

    const int xpart = (gw + 3 * sw) * 192 + 64 + co + slot * 576;

    float4 acc = make_float4(0.f, 0.f, 0.f, 0.f);
    float s = 0.0f;

    for (int kh = 0; kh < KS; kh++) {
        int ny = gh + 3 * (sh + kh);
        const float* kp = qkv + ny * (WW * 192) + xpart;
        const float* bp = bias_h + (sh + kh - ih + 12) * 25;
        #pragma unroll
        for (int i = 0; i < 3; i++) {          // kw = 4*i + slot : 0..11
            float4 k4 = *(const float4*)(kp + i * 2304);
            float4 v4 = *(const float4*)(kp + i * 2304 + 64);
            float p = q4.x * k4.x + q4.y * k4.y + q4.z * k4.z + q4.w * k4.w;
            p = dpp_add<0xB1>(p);
            p = dpp_add<0x4E>(p);              // p = 16-dim dot (quad sum)
            float e = __expf(p + bp[4 * i + slot]);
            s += e;
            acc.x += e * v4.x; acc.y += e * v4.y; acc.z += e * v4.z; acc.w += e * v4.w;
        }
        if (slot == 0) {                        // tail kw = 12 (quad-uniform branch)
            float4 k4 = *(const float4*)(kp + 3 * 2304);
            float4 v4 = *(const float4*)(kp + 3 * 2304 + 64);
            float p = q4.x * k4.x + q4.y * k4.y + q4.z * k4.z + q4.w * k4.w;
            p = dpp_add<0xB1>(p);
            p = dpp_add<0x4E>(p);
            float e = __expf(p + bp[12]);
            s += e;
            acc.x += e * v4.x; acc.y += e * v4.y; acc.z += e * v4.z; acc.w += e * v4.w;
        }
    }

    s = dpp_add<0x128>(s);  s = dpp_add<0x124>(s);
    acc.x = dpp_add<0x128>(acc.x); acc.x = dpp_add<0x124>(acc.x);
    acc.y = dpp_add<0x128>(acc.y); acc.y = dpp_add<0x124>(acc.y);
    acc.z = dpp_add<0x128>(acc.z); acc.z = dpp_add<0x124>(acc.z);
    acc.w = dpp_add<0x128>(acc.w); acc.w = dpp_add<0x124>(acc.w);

    if (slot == 0) {
        float inv = 1.0f / s;
        *(float4*)&out[token * CC + co] =
            make_float4(acc.x * inv, acc.y * inv, acc.z * inv, acc.w * inv);
    }
}

// ---------------- Fused proj+resid -> LN2 -> fc1+gelu -> fc2+resid ----------
// v3, driven by the R8/R9 controlled pair: time tracks ISSUED-L1 traffic,
// which is (weight bytes) / (rows per thread). R8 = 2 rows -> 42 us;
// R9 = 1 row -> 89 us (2x, as the model demands). v3 = 4 ROWS PER THREAD:
// 32 tok/block, 128 threads = 16 tc x 8 tr, each thread 4 rows x 4 cols,
// float4 weight loads reused across 4 rows in registers -> issued-L1 per
// token HALF of R8. Occupancy is intentionally low (~0.6 wave/SIMD): R8
// proved 1.1 w/SIMD suffices; R9 proved TLP doesn't pay here.
// Pitch 36 (144 B) makes &buf[k][r0] 16B-aligned (r0 = 4*tr) -> ds_read_b128.
__global__ __launch_bounds__(128) void mlp_fused_kernel(const float* __restrict__ attn_out,
                                                        const float* __restrict__ x,
                                                        const float* __restrict__ proj_w,
                                                        const float* __restrict__ proj_b,
                                                        const float* __restrict__ n2g,
                                                        const float* __restrict__ n2b,
                                                        const float* __restrict__ fc1_w,
                                                        const float* __restrict__ fc1_b,
                                                        const float* __restrict__ fc2_w,
                                                        const float* __restrict__ fc2_b,
                                                        float* __restrict__ out) {
    __shared__ float Ast[64][36];    // attn_out^T tile      (9.2 KB)
    __shared__ float X2T[64][36];    // x2^T -> h2^T          (9.2 KB)
    __shared__ float Hid[256][36];   // hidden^T              (36.9 KB)

    const int t0 = blockIdx.x * 32;
    const int tid = threadIdx.x;
    const int tc = tid & 15;         // col group: cols 4tc..4tc+3
    const int tr = tid >> 4;         // row group 0..7: rows 4tr..4tr+3
    const int r0 = tr * 4;
    const int c  = tc * 4;

    // stage attn_out tile transposed: 512 float4s, 4 per thread, coalesced
    #pragma unroll
    for (int j = 0; j < 4; j++) {
        int idx = tid + 128 * j;                 // float4 index 0..511
        float4 v = ((const float4*)attn_out)[t0 * 16 + idx];
        int row = idx >> 4, cc = (idx & 15) * 4;
        Ast[cc][row] = v.x; Ast[cc + 1][row] = v.y;
        Ast[cc + 2][row] = v.z; Ast[cc + 3][row] = v.w;
    }
    __syncthreads();

    // ---- proj + residual(x): x2 rows r0..r0+3 kept in registers a[4] ----
    float4 pb = *(const float4*)&proj_b[c];
    float4 a[4] = {pb, pb, pb, pb};
    #pragma unroll 8
    for (int k = 0; k < 64; k++) {
        float4 aa = *(const float4*)&Ast[k][r0];
        float  ar[4] = {aa.x, aa.y, aa.z, aa.w};
        float4 w = *(const float4*)&proj_w[k * 64 + c];
        #pragma unroll
        for (int i = 0; i < 4; i++) {
            a[i].x += ar[i] * w.x; a[i].y += ar[i] * w.y;
            a[i].z += ar[i] * w.z; a[i].w += ar[i] * w.w;
        }
    }
    #pragma unroll
    for (int i = 0; i < 4; i++) {
        float4 xr = *(const float4*)&x[(t0 + r0 + i) * 64 + c];
        a[i].x += xr.x; a[i].y += xr.y; a[i].z += xr.z; a[i].w += xr.w;
        X2T[c][r0 + i] = a[i].x; X2T[c + 1][r0 + i] = a[i].y;
        X2T[c + 2][r0 + i] = a[i].z; X2T[c + 3][r0 + i] = a[i].w;
    }
    __syncthreads();

    // ---- LN2 in place on X2T: 128 thr = 32 rows x 4 lanes, 16 ch/lane ----
    {
        int r  = tid >> 2;
        int c0 = (tid & 3) * 16;
        float v[16];
        float s = 0.0f;
        #pragma unroll
        for (int j = 0; j < 16; j++) { v[j] = X2T[c0 + j][r]; s += v[j]; }
        s = dpp_add<0xB1>(s); s = dpp_add<0x4E>(s);      // quad sum = 64 ch
        float mu = s * (1.0f / 64.0f);
        float s2 = 0.0f;
        #pragma unroll
        for (int j = 0; j < 16; j++) { float d = v[j] - mu; s2 += d * d; }
        s2 = dpp_add<0xB1>(s2); s2 = dpp_add<0x4E>(s2);
        float inv = rsqrtf(s2 * (1.0f / 64.0f) + 1e-5f);
        #pragma unroll
        for (int j = 0; j < 16; j++)
            X2T[c0 + j][r] = (v[j] - mu) * inv * n2g[c0 + j] + n2b[c0 + j];
    }
    __syncthreads();

    // ---- fc1 + gelu -> Hid. Thread: 4 rows x 16 cols (4 gg x float4) ----
    float4 h[4][4];
    #pragma unroll
    for (int gg = 0; gg < 4; gg++) {
        float4 bb = *(const float4*)&fc1_b[c + gg * 64];
        #pragma unroll
        for (int i = 0; i < 4; i++) h[i][gg] = bb;
    }
    #pragma unroll 4
    for (int k = 0; k < 64; k++) {
        float4 aa = *(const float4*)&X2T[k][r0];
        float  ar[4] = {aa.x, aa.y, aa.z, aa.w};
        #pragma unroll
        for (int gg = 0; gg < 4; gg++) {
            float4 w = *(const float4*)&fc1_w[k * 256 + c + gg * 64];
            #pragma unroll
            for (int i = 0; i < 4; i++) {
                h[i][gg].x += ar[i] * w.x; h[i][gg].y += ar[i] * w.y;
                h[i][gg].z += ar[i] * w.z; h[i][gg].w += ar[i] * w.w;
            }
        }
    }
    #define GELU1(v) v = 0.5f * v * (1.0f + erff(v * 0.70710678118f))
    #pragma unroll
    for (int i = 0; i < 4; i++)
        #pragma unroll
        for (int gg = 0; gg < 4; gg++) {
            GELU1(h[i][gg].x); GELU1(h[i][gg].y); GELU1(h[i][gg].z); GELU1(h[i][gg].w);
        }
    #undef GELU1
    // write hidden^T as float4 down rows: Hid[col][r0..r0+3]
    #pragma unroll
    for (int gg = 0; gg < 4; gg++) {
        #pragma unroll
        for (int j = 0; j < 4; j++) {
            *(float4*)&Hid[c + gg * 64 + j][r0] =
                make_float4(h[0][gg + 0].x, 0.f, 0.f, 0.f); // placeholder, fixed below
        }
    }
    // (the make_float4 above is replaced component-correct here)
    #pragma unroll
    for (int gg = 0; gg < 4; gg++) {
        float4 col0 = make_float4(h[0][gg].x, h[1][gg].x, h[2][gg].x, h[3][gg].x);
        float4 col1 = make_float4(h[0][gg].y, h[1][gg].y, h[2][gg].y, h[3][gg].y);
        float4 col2 = make_float4(h[0][gg].z, h[1][gg].z, h[2][gg].z, h[3][gg].z);
        float4 col3 = make_float4(h[0][gg].w, h[1][gg].w, h[2][gg].w, h[3][gg].w);
        *(float4*)&Hid[c + gg * 64 + 0][r0] = col0;
        *(float4*)&Hid[c + gg * 64 + 1][r0] = col1;
        *(float4*)&Hid[c + gg * 64 + 2][r0] = col2;
        *(float4*)&Hid[c + gg * 64 + 3][r0] = col3;
    }
    __syncthreads();

    // ---- fc2 + residual(x2 from registers a[4]) ----
    float4 ob = *(const float4*)&fc2_b[c];
    float4 o[4] = {ob, ob, ob, ob};
    #pragma unroll 8
    for (int k = 0; k < 256; k++) {
        float4 aa = *(const float4*)&Hid[k][r0];
        float  ar[4] = {aa.x, aa.y, aa.z, aa.w};
        float4 w = *(const float4*)&fc2_w[k * 64 + c];
        #pragma unroll
        for (int i = 0; i < 4; i++) {
            o[i].x += ar[i] * w.x; o[i].y += ar[i] * w.y;
            o[i].z += ar[i] * w.z; o[i].w += ar[i] * w.w;
        }
    }
    #pragma unroll
    for (int i = 0; i < 4; i++) {
        o[i].x += a[i].x; o[i].y += a[i].y; o[i].z += a[i].z; o[i].w += a[i].w;
        *(float4*)&out[(t0 + r0 + i) * 64 + c] = o[i];
    }
}

extern "C" void kernel_launch(void* const* d_in, const int* in_sizes, int n_in,
                              void* d_out, int out_size, void* d_ws, size_t ws_size,
                              hipStream_t stream) {
    const float* x       = (const float*)d_in[0];
    const float* norm1_g = (const float*)d_in[1];
    const float* norm1_b = (const float*)d_in[2];
    const float* qkv_w   = (const float*)d_in[3];
    const float* qkv_b   = (const float*)d_in[4];
    const float* rpb     = (const float*)d_in[5];
    const float* proj_w  = (const float*)d_in[6];
    const float* proj_b  = (const float*)d_in[7];
    const float* norm2_g = (const float*)d_in[8];
    const float* norm2_b = (const float*)d_in[9];
    const float* fc1_w   = (const float*)d_in[10];
    const float* fc1_b   = (const float*)d_in[11];
    const float* fc2_w   = (const float*)d_in[12];
    const float* fc2_b   = (const float*)d_in[13];
    float* out = (float*)d_out;

    float* ws = (float*)d_ws;
    float* qkv      = ws;                      // 9216*192
    float* attn_out = qkv + NTOK * 192;        // 9216*64

    dim3 blk(256);
    // 1. qkv = LN1(x) @ qkv_w + qkv_b   (q pre-scaled)
    ln_gemm_kernel<<<dim3(NTOK / 32, 3), blk, 0, stream>>>(x, norm1_g, norm1_b, qkv_w, qkv_b, qkv);
    // 2. neighborhood attention (1 token/wave; block = 4 window-sharing tokens)
    na_attn_kernel<<<NTOK / 4, blk, 0, stream>>>(qkv, rpb, attn_out);
    // 3. out = fused MLP, 32 tok/block, 128 thr, 4 rows/thread (issued-L1 / 2)
    mlp_fused_kernel<<<NTOK / 32, dim3(128), 0, stream>>>(attn_out, x, proj_w, proj_b,
                                                          norm2_g, norm2_b, fc1_w, fc1_b,
                                                          fc2_w, fc2_b, out);
}